// Round 4
// baseline (448.545 us; speedup 1.0000x reference)
//
#include <hip/hip_runtime.h>

typedef __attribute__((ext_vector_type(4))) float f4;
typedef __attribute__((ext_vector_type(8))) short s8;   // 8 bf16 (4 VGPRs) MFMA frag

#define EPS 1e-5f

__device__ __forceinline__ unsigned short f2bf(float f) {
    union { float f; unsigned u; } v; v.f = f;
    unsigned u = v.u;
    return (unsigned short)((u + 0x7fffu + ((u >> 16) & 1u)) >> 16);   // RNE
}
__device__ __forceinline__ unsigned pack2(float a, float b) {
    return (unsigned)f2bf(a) | ((unsigned)f2bf(b) << 16);
}
__device__ __forceinline__ s8 pack8(f4 a, f4 b) {
    union { s8 v; unsigned u[4]; } r;
    r.u[0] = pack2(a[0], a[1]); r.u[1] = pack2(a[2], a[3]);
    r.u[2] = pack2(b[0], b[1]); r.u[3] = pack2(b[2], b[3]);
    return r.v;
}

// =================== prep1 (merged): weight frag-linear bf16 + A/cvec ===================
// FL layout: FL[((ksg*16 + ct)*64 + lane)*8 + j] = W[ct*16 + (lane&15)][ksg*32 + (lane>>4)*8 + j]
__global__ __launch_bounds__(256) void k_prep1(const float* __restrict__ text_w,
                                               const float* __restrict__ bio_w,
                                               const float* __restrict__ out_w,
                                               const float* __restrict__ in_proj_w,
                                               const float* __restrict__ in_proj_b,
                                               const float* __restrict__ out_b,
                                               unsigned short* __restrict__ twFL,
                                               unsigned short* __restrict__ bwFL,
                                               float* __restrict__ A,
                                               float* __restrict__ cvec) {
    int b = blockIdx.x, t = threadIdx.x;
    if (b < 96) {                       // text_w [256][768] -> 24 ksteps x 16 ct
        int idx = b * 256 + t;
        int ksg = idx >> 10;
        int rem = idx & 1023;
        int ct = rem >> 6, lane = rem & 63;
        int n  = ct * 16 + (lane & 15);
        int k0 = ksg * 32 + ((lane >> 4) << 3);
        const float* src = &text_w[n * 768 + k0];
        f4 a = *(const f4*)src, c = *(const f4*)(src + 4);
        unsigned* dst = (unsigned*)&twFL[idx * 8];
        dst[0] = pack2(a[0], a[1]); dst[1] = pack2(a[2], a[3]);
        dst[2] = pack2(c[0], c[1]); dst[3] = pack2(c[2], c[3]);
    } else if (b < 100) {               // bio_w [256][32] -> 1 kstep x 16 ct
        int idx = (b - 96) * 256 + t;
        int ct = idx >> 6, lane = idx & 63;
        int n  = ct * 16 + (lane & 15);
        int k0 = (lane >> 4) << 3;
        const float* src = &bio_w[n * 32 + k0];
        f4 a = *(const f4*)src, c = *(const f4*)(src + 4);
        unsigned* dst = (unsigned*)&bwFL[idx * 8];
        dst[0] = pack2(a[0], a[1]); dst[1] = pack2(a[2], a[3]);
        dst[2] = pack2(c[0], c[1]); dst[3] = pack2(c[2], c[3]);
    } else {                            // A = out_w @ Wv, cvec = out_w @ bv + out_b
        __shared__ float srow[256];
        __shared__ float red[256];
        int i = b - 100, j = t;
        srow[j] = out_w[i * 256 + j];
        __syncthreads();
        float acc = 0.f;
#pragma unroll 16
        for (int k = 0; k < 256; k++)
            acc = fmaf(srow[k], in_proj_w[(512 + k) * 256 + j], acc);
        A[i * 256 + j] = acc;
        red[j] = srow[j] * in_proj_b[512 + j];
        __syncthreads();
        for (int s = 128; s > 0; s >>= 1) {
            if (j < s) red[j] += red[j + s];
            __syncthreads();
        }
        if (j == 0) cvec[i] = red[0] + out_b[i];
    }
}

// =================== prep2: PQ weights (frag-linear bf16, LN-gain folded) + dvec ===================
__global__ __launch_bounds__(256) void k_prep_PQ(const float* __restrict__ cls1_w,
                                                 const float* __restrict__ cls1_b,
                                                 const float* __restrict__ A,
                                                 const float* __restrict__ cvec,
                                                 const float* __restrict__ ln_text_g,
                                                 const float* __restrict__ ln_text_b,
                                                 const float* __restrict__ ln_bio_g,
                                                 const float* __restrict__ ln_bio_b,
                                                 unsigned short* __restrict__ pqFL,
                                                 float* __restrict__ dvec) {
    __shared__ float w1[256], w2[256], red[256];
    int i = blockIdx.x, j = threadIdx.x;
    w1[j] = cls1_w[i * 512 + j];
    w2[j] = cls1_w[i * 512 + 256 + j];
    __syncthreads();
    float rp = 0.f, rq = 0.f;
#pragma unroll 8
    for (int k = 0; k < 256; k++) {
        float a = A[k * 256 + j];
        rp = fmaf(w1[k], a, rp);
        rq = fmaf(w2[k], a, rq);
    }
    int ct   = i >> 4;
    int lane = (i & 15) | (((j >> 3) & 3) << 4);
    int jj   = j & 7;
    int ks1  = j >> 5;
    pqFL[(((ks1     ) * 16 + ct) * 64 + lane) * 8 + jj] = f2bf(rp * ln_text_g[j]);
    pqFL[(((ks1 + 8 ) * 16 + ct) * 64 + lane) * 8 + jj] = f2bf(rq * ln_bio_g[j]);
    red[j] = rp * ln_text_b[j] + rq * ln_bio_b[j] + (w1[j] + w2[j]) * cvec[j];
    __syncthreads();
    for (int s = 128; s > 0; s >>= 1) {
        if (j < s) red[j] += red[j + s];
        __syncthreads();
    }
    if (j == 0) dvec[i] = red[0] + cls1_b[i];
}

// =================== main fused MFMA kernel ===================
// 64 rows/block, 512 threads = 8 waves: wave = (cs = w&3 col-slice of 64, rh = w>>2 row-half of 32).
// Stage B reads text A-frags DIRECTLY from global (no LDS staging, no barriers in K-loop):
// lane's 32B k-segment is contiguous; 4 cs-waves re-read the same lines via L1/L2.
// No long-lived prefetch arrays -> no spills (round-3 lesson: WRITE_SIZE 53MB was scratch).
__global__ __launch_bounds__(512, 4) void k_main(
    const float* __restrict__ bio, const float* __restrict__ text,
    const float* __restrict__ bio_b, const float* __restrict__ text_b,
    const float* __restrict__ cls_ln_g, const float* __restrict__ cls_ln_b,
    const float* __restrict__ cls2_w, const float* __restrict__ cls2_b,
    const unsigned short* __restrict__ twFL, const unsigned short* __restrict__ bwFL,
    const unsigned short* __restrict__ pqFL, const float* __restrict__ dvec,
    float* __restrict__ out)
{
    // row stride 520 u16 = 1040 B: 16B-aligned rows; frag reads land 2-way max on banks
    __shared__ __align__(16) unsigned short s_n[64][520];  // 66.6 KB; [row][k] n_t 0..255 | n_b 256..511
    __shared__ float s_red[4][64][2];                      // 2 KB per-colslice row partials

    const int tid  = threadIdx.x;
    const int wv   = tid >> 6;
    const int cs   = wv & 3;          // col slice: cols [cs*64, cs*64+64)
    const int rh   = wv >> 2;         // row half: rows [rh*32, rh*32+32)
    const int lane = tid & 63;
    const int q    = lane >> 4;
    const int lr   = lane & 15;
    const int R0   = blockIdx.x * 64;

    f4 acc[2][4];
    float s1[2][4], s2[2][4], m_[2][4], iv_[2][4];

    // ---------------- stage A: x_b = bio @ bio_w.T + bio_b ; n_b ----------------
    {
        f4 bioA[2], bioB[2];
#pragma unroll
        for (int rt = 0; rt < 2; rt++) {
            const float* p = &bio[(size_t)(R0 + rh * 32 + rt * 16 + lr) * 32 + q * 8];
            bioA[rt] = *(const f4*)p;
            bioB[rt] = *(const f4*)(p + 4);
        }
        s8 bfrb[4];
#pragma unroll
        for (int c = 0; c < 4; c++)
            bfrb[c] = *(const s8*)&bwFL[((cs * 4 + c) * 64 + lane) * 8];
#pragma unroll
        for (int rt = 0; rt < 2; rt++)
#pragma unroll
            for (int c = 0; c < 4; c++) acc[rt][c] = (f4){0.f, 0.f, 0.f, 0.f};
#pragma unroll
        for (int rt = 0; rt < 2; rt++) {
            s8 af = pack8(bioA[rt], bioB[rt]);
#pragma unroll
            for (int c = 0; c < 4; c++)
                acc[rt][c] = __builtin_amdgcn_mfma_f32_16x16x32_bf16(af, bfrb[c], acc[rt][c], 0, 0, 0);
        }
    }
#pragma unroll
    for (int rt = 0; rt < 2; rt++)
#pragma unroll
        for (int r = 0; r < 4; r++) { s1[rt][r] = 0.f; s2[rt][r] = 0.f; }
#pragma unroll
    for (int rt = 0; rt < 2; rt++)
#pragma unroll
        for (int c = 0; c < 4; c++) {
            float bb = bio_b[cs * 64 + c * 16 + lr];
#pragma unroll
            for (int r = 0; r < 4; r++) {
                float x = acc[rt][c][r] + bb;
                acc[rt][c][r] = x;
                s1[rt][r] += x; s2[rt][r] += x * x;
            }
        }
#pragma unroll
    for (int off = 1; off < 16; off <<= 1)
#pragma unroll
        for (int rt = 0; rt < 2; rt++)
#pragma unroll
            for (int r = 0; r < 4; r++) {
                s1[rt][r] += __shfl_xor(s1[rt][r], off, 64);
                s2[rt][r] += __shfl_xor(s2[rt][r], off, 64);
            }
    if (lr == 0)
#pragma unroll
        for (int rt = 0; rt < 2; rt++)
#pragma unroll
            for (int r = 0; r < 4; r++) {
                int row = rh * 32 + rt * 16 + q * 4 + r;
                s_red[cs][row][0] = s1[rt][r];
                s_red[cs][row][1] = s2[rt][r];
            }
    __syncthreads();
#pragma unroll
    for (int rt = 0; rt < 2; rt++)
#pragma unroll
        for (int r = 0; r < 4; r++) {
            int row = rh * 32 + rt * 16 + q * 4 + r;
            float t1 = s_red[0][row][0] + s_red[1][row][0] + s_red[2][row][0] + s_red[3][row][0];
            float t2 = s_red[0][row][1] + s_red[1][row][1] + s_red[2][row][1] + s_red[3][row][1];
            float mm = t1 * (1.f / 256.f);
            float vv = t2 * (1.f / 256.f) - mm * mm;
            m_[rt][r]  = mm;
            iv_[rt][r] = rsqrtf(vv + EPS);
        }
#pragma unroll
    for (int rt = 0; rt < 2; rt++)
#pragma unroll
        for (int c = 0; c < 4; c++) {
            int col = cs * 64 + c * 16 + lr;
#pragma unroll
            for (int r = 0; r < 4; r++)
                s_n[rh * 32 + rt * 16 + q * 4 + r][256 + col] =
                    f2bf((acc[rt][c][r] - m_[rt][r]) * iv_[rt][r]);
        }

    // ---------------- stage B: x_t = text @ text_w.T + text_b (K=768, no LDS, no barriers) ----------------
#pragma unroll
    for (int rt = 0; rt < 2; rt++)
#pragma unroll
        for (int c = 0; c < 4; c++) acc[rt][c] = (f4){0.f, 0.f, 0.f, 0.f};
    {
        const float* tb0 = &text[(size_t)(R0 + rh * 32 + lr) * 768 + q * 8];
        const float* tb1 = tb0 + 16 * 768;
        // depth-1 pipeline on A-frags (transient regs only)
        f4 a0lo = *(const f4*)tb0, a0hi = *(const f4*)(tb0 + 4);
        f4 a1lo = *(const f4*)tb1, a1hi = *(const f4*)(tb1 + 4);
        for (int ks = 0; ks < 24; ks++) {
            f4 n0lo, n0hi, n1lo, n1hi;
            if (ks < 23) {
                const float* p0 = tb0 + (ks + 1) * 32;
                const float* p1 = tb1 + (ks + 1) * 32;
                n0lo = *(const f4*)p0; n0hi = *(const f4*)(p0 + 4);
                n1lo = *(const f4*)p1; n1hi = *(const f4*)(p1 + 4);
            }
            s8 bfr[4];
#pragma unroll
            for (int c = 0; c < 4; c++)
                bfr[c] = *(const s8*)&twFL[((ks * 16 + cs * 4 + c) * 64 + lane) * 8];
            {
                s8 af0 = pack8(a0lo, a0hi);
                s8 af1 = pack8(a1lo, a1hi);
#pragma unroll
                for (int c = 0; c < 4; c++) {
                    acc[0][c] = __builtin_amdgcn_mfma_f32_16x16x32_bf16(af0, bfr[c], acc[0][c], 0, 0, 0);
                    acc[1][c] = __builtin_amdgcn_mfma_f32_16x16x32_bf16(af1, bfr[c], acc[1][c], 0, 0, 0);
                }
            }
            a0lo = n0lo; a0hi = n0hi; a1lo = n1lo; a1hi = n1hi;
        }
    }
    // bias + LN stats for text
#pragma unroll
    for (int rt = 0; rt < 2; rt++)
#pragma unroll
        for (int r = 0; r < 4; r++) { s1[rt][r] = 0.f; s2[rt][r] = 0.f; }
#pragma unroll
    for (int rt = 0; rt < 2; rt++)
#pragma unroll
        for (int c = 0; c < 4; c++) {
            float bb = text_b[cs * 64 + c * 16 + lr];
#pragma unroll
            for (int r = 0; r < 4; r++) {
                float x = acc[rt][c][r] + bb;
                acc[rt][c][r] = x;
                s1[rt][r] += x; s2[rt][r] += x * x;
            }
        }
#pragma unroll
    for (int off = 1; off < 16; off <<= 1)
#pragma unroll
        for (int rt = 0; rt < 2; rt++)
#pragma unroll
            for (int r = 0; r < 4; r++) {
                s1[rt][r] += __shfl_xor(s1[rt][r], off, 64);
                s2[rt][r] += __shfl_xor(s2[rt][r], off, 64);
            }
    __syncthreads();   // all waves past stage-A s_red reads; safe to rewrite
    if (lr == 0)
#pragma unroll
        for (int rt = 0; rt < 2; rt++)
#pragma unroll
            for (int r = 0; r < 4; r++) {
                int row = rh * 32 + rt * 16 + q * 4 + r;
                s_red[cs][row][0] = s1[rt][r];
                s_red[cs][row][1] = s2[rt][r];
            }
    __syncthreads();
#pragma unroll
    for (int rt = 0; rt < 2; rt++)
#pragma unroll
        for (int r = 0; r < 4; r++) {
            int row = rh * 32 + rt * 16 + q * 4 + r;
            float t1 = s_red[0][row][0] + s_red[1][row][0] + s_red[2][row][0] + s_red[3][row][0];
            float t2 = s_red[0][row][1] + s_red[1][row][1] + s_red[2][row][1] + s_red[3][row][1];
            float mm = t1 * (1.f / 256.f);
            float vv = t2 * (1.f / 256.f) - mm * mm;
            m_[rt][r]  = mm;
            iv_[rt][r] = rsqrtf(vv + EPS);
        }
#pragma unroll
    for (int rt = 0; rt < 2; rt++)
#pragma unroll
        for (int c = 0; c < 4; c++) {
            int col = cs * 64 + c * 16 + lr;
#pragma unroll
            for (int r = 0; r < 4; r++)
                s_n[rh * 32 + rt * 16 + q * 4 + r][col] =
                    f2bf((acc[rt][c][r] - m_[rt][r]) * iv_[rt][r]);
        }
    __syncthreads();   // full s_n = [n_t | n_b] visible to all waves

    // ---------------- stage D: z = Wpq @ [n_t ; n_b] + dvec (K=512) ----------------
#pragma unroll
    for (int rt = 0; rt < 2; rt++)
#pragma unroll
        for (int c = 0; c < 4; c++) {
            float dv = dvec[cs * 64 + c * 16 + lr];
            acc[rt][c] = (f4){dv, dv, dv, dv};
        }
#pragma unroll 4
    for (int ks = 0; ks < 16; ks++) {
        s8 bfr[4];
#pragma unroll
        for (int c = 0; c < 4; c++)
            bfr[c] = *(const s8*)&pqFL[((ks * 16 + cs * 4 + c) * 64 + lane) * 8];
#pragma unroll
        for (int rt = 0; rt < 2; rt++) {
            s8 af = *(const s8*)&s_n[rh * 32 + rt * 16 + lr][ks * 32 + q * 8];
#pragma unroll
            for (int c = 0; c < 4; c++)
                acc[rt][c] = __builtin_amdgcn_mfma_f32_16x16x32_bf16(af, bfr[c], acc[rt][c], 0, 0, 0);
        }
    }

    // ---------------- epilogue: LN(z), relu, cls2 ----------------
#pragma unroll
    for (int rt = 0; rt < 2; rt++)
#pragma unroll
        for (int r = 0; r < 4; r++) { s1[rt][r] = 0.f; s2[rt][r] = 0.f; }
#pragma unroll
    for (int rt = 0; rt < 2; rt++)
#pragma unroll
        for (int c = 0; c < 4; c++)
#pragma unroll
            for (int r = 0; r < 4; r++) {
                float x = acc[rt][c][r];
                s1[rt][r] += x; s2[rt][r] += x * x;
            }
#pragma unroll
    for (int off = 1; off < 16; off <<= 1)
#pragma unroll
        for (int rt = 0; rt < 2; rt++)
#pragma unroll
            for (int r = 0; r < 4; r++) {
                s1[rt][r] += __shfl_xor(s1[rt][r], off, 64);
                s2[rt][r] += __shfl_xor(s2[rt][r], off, 64);
            }
    __syncthreads();
    if (lr == 0)
#pragma unroll
        for (int rt = 0; rt < 2; rt++)
#pragma unroll
            for (int r = 0; r < 4; r++) {
                int row = rh * 32 + rt * 16 + q * 4 + r;
                s_red[cs][row][0] = s1[rt][r];
                s_red[cs][row][1] = s2[rt][r];
            }
    __syncthreads();
#pragma unroll
    for (int rt = 0; rt < 2; rt++)
#pragma unroll
        for (int r = 0; r < 4; r++) {
            int row = rh * 32 + rt * 16 + q * 4 + r;
            float t1 = s_red[0][row][0] + s_red[1][row][0] + s_red[2][row][0] + s_red[3][row][0];
            float t2 = s_red[0][row][1] + s_red[1][row][1] + s_red[2][row][1] + s_red[3][row][1];
            float mm = t1 * (1.f / 256.f);
            float vv = t2 * (1.f / 256.f) - mm * mm;
            m_[rt][r]  = mm;
            iv_[rt][r] = rsqrtf(vv + EPS);
        }
    float po0[2][4], po1[2][4];
#pragma unroll
    for (int rt = 0; rt < 2; rt++)
#pragma unroll
        for (int r = 0; r < 4; r++) { po0[rt][r] = 0.f; po1[rt][r] = 0.f; }
#pragma unroll
    for (int rt = 0; rt < 2; rt++)
#pragma unroll
        for (int c = 0; c < 4; c++) {
            int col = cs * 64 + c * 16 + lr;
            float gg = cls_ln_g[col], bb = cls_ln_b[col];
            float c0 = cls2_w[col],   c1 = cls2_w[256 + col];
#pragma unroll
            for (int r = 0; r < 4; r++) {
                float h = fmaxf((acc[rt][c][r] - m_[rt][r]) * iv_[rt][r] * gg + bb, 0.f);
                po0[rt][r] = fmaf(h, c0, po0[rt][r]);
                po1[rt][r] = fmaf(h, c1, po1[rt][r]);
            }
        }
#pragma unroll
    for (int off = 1; off < 16; off <<= 1)
#pragma unroll
        for (int rt = 0; rt < 2; rt++)
#pragma unroll
            for (int r = 0; r < 4; r++) {
                po0[rt][r] += __shfl_xor(po0[rt][r], off, 64);
                po1[rt][r] += __shfl_xor(po1[rt][r], off, 64);
            }
    __syncthreads();
    if (lr == 0)
#pragma unroll
        for (int rt = 0; rt < 2; rt++)
#pragma unroll
            for (int r = 0; r < 4; r++) {
                int row = rh * 32 + rt * 16 + q * 4 + r;
                s_red[cs][row][0] = po0[rt][r];
                s_red[cs][row][1] = po1[rt][r];
            }
    __syncthreads();
    if (tid < 128) {
        int row = tid >> 1, comp = tid & 1;
        float v = s_red[0][row][comp] + s_red[1][row][comp] +
                  s_red[2][row][comp] + s_red[3][row][comp];
        out[(size_t)(R0 + row) * 2 + comp] = v + cls2_b[comp];
    }
}

// ======================= launch =======================
extern "C" void kernel_launch(void* const* d_in, const int* in_sizes, int n_in,
                              void* d_out, int out_size, void* d_ws, size_t ws_size,
                              hipStream_t stream) {
    const float* bio       = (const float*)d_in[0];
    const float* text      = (const float*)d_in[1];
    const float* bio_w     = (const float*)d_in[2];
    const float* bio_b     = (const float*)d_in[3];
    const float* text_w    = (const float*)d_in[4];
    const float* text_b    = (const float*)d_in[5];
    const float* ln_bio_g  = (const float*)d_in[6];
    const float* ln_bio_b  = (const float*)d_in[7];
    const float* ln_text_g = (const float*)d_in[8];
    const float* ln_text_b = (const float*)d_in[9];
    const float* in_proj_w = (const float*)d_in[10];
    const float* in_proj_b = (const float*)d_in[11];
    const float* out_w     = (const float*)d_in[12];
    const float* out_b     = (const float*)d_in[13];
    const float* cls1_w    = (const float*)d_in[14];
    const float* cls1_b    = (const float*)d_in[15];
    const float* cls_ln_g  = (const float*)d_in[16];
    const float* cls_ln_b  = (const float*)d_in[17];
    const float* cls2_w    = (const float*)d_in[18];
    const float* cls2_b    = (const float*)d_in[19];
    float* out = (float*)d_out;

    float* ws   = (float*)d_ws;
    float* A    = ws;                 // 65536 fp32
    float* cvec = ws + 65536;         // 256
    float* dvec = ws + 65792;         // 256
    unsigned short* us   = (unsigned short*)(ws + 66048);
    unsigned short* twFL = us;            // 196608 bf16
    unsigned short* bwFL = us + 196608;   // 8192
    unsigned short* pqFL = us + 204800;   // 131072

    k_prep1  <<<356, 256, 0, stream>>>(text_w, bio_w, out_w, in_proj_w, in_proj_b, out_b,
                                       twFL, bwFL, A, cvec);
    k_prep_PQ<<<256, 256, 0, stream>>>(cls1_w, cls1_b, A, cvec,
                                       ln_text_g, ln_text_b, ln_bio_g, ln_bio_b,
                                       pqFL, dvec);

    int nrows = in_sizes[0] / 32;     // 65536
    k_main<<<nrows / 64, 512, 0, stream>>>(bio, text, bio_b, text_b,
                                           cls_ln_g, cls_ln_b, cls2_w, cls2_b,
                                           twFL, bwFL, pqFL, dvec, out);
}

// Round 5
// 427.487 us; speedup vs baseline: 1.0493x; 1.0493x over previous
//
#include <hip/hip_runtime.h>

typedef __attribute__((ext_vector_type(4))) float f4;
typedef __attribute__((ext_vector_type(8))) short s8;   // 8 bf16 (4 VGPRs) MFMA frag

#define EPS 1e-5f

__device__ __forceinline__ unsigned short f2bf(float f) {
    union { float f; unsigned u; } v; v.f = f;
    unsigned u = v.u;
    return (unsigned short)((u + 0x7fffu + ((u >> 16) & 1u)) >> 16);   // RNE
}
__device__ __forceinline__ unsigned pack2(float a, float b) {
    return (unsigned)f2bf(a) | ((unsigned)f2bf(b) << 16);
}
__device__ __forceinline__ s8 pack8(f4 a, f4 b) {
    union { s8 v; unsigned u[4]; } r;
    r.u[0] = pack2(a[0], a[1]); r.u[1] = pack2(a[2], a[3]);
    r.u[2] = pack2(b[0], b[1]); r.u[3] = pack2(b[2], b[3]);
    return r.v;
}

// =================== prep1 (merged): weight frag-linear bf16 + A/cvec ===================
// FL layout: FL[((ksg*16 + ct)*64 + lane)*8 + j] = W[ct*16 + (lane&15)][ksg*32 + (lane>>4)*8 + j]
__global__ __launch_bounds__(256) void k_prep1(const float* __restrict__ text_w,
                                               const float* __restrict__ bio_w,
                                               const float* __restrict__ out_w,
                                               const float* __restrict__ in_proj_w,
                                               const float* __restrict__ in_proj_b,
                                               const float* __restrict__ out_b,
                                               unsigned short* __restrict__ twFL,
                                               unsigned short* __restrict__ bwFL,
                                               float* __restrict__ A,
                                               float* __restrict__ cvec) {
    int b = blockIdx.x, t = threadIdx.x;
    if (b < 96) {                       // text_w [256][768] -> 24 ksteps x 16 ct
        int idx = b * 256 + t;
        int ksg = idx >> 10;
        int rem = idx & 1023;
        int ct = rem >> 6, lane = rem & 63;
        int n  = ct * 16 + (lane & 15);
        int k0 = ksg * 32 + ((lane >> 4) << 3);
        const float* src = &text_w[n * 768 + k0];
        f4 a = *(const f4*)src, c = *(const f4*)(src + 4);
        unsigned* dst = (unsigned*)&twFL[idx * 8];
        dst[0] = pack2(a[0], a[1]); dst[1] = pack2(a[2], a[3]);
        dst[2] = pack2(c[0], c[1]); dst[3] = pack2(c[2], c[3]);
    } else if (b < 100) {               // bio_w [256][32] -> 1 kstep x 16 ct
        int idx = (b - 96) * 256 + t;
        int ct = idx >> 6, lane = idx & 63;
        int n  = ct * 16 + (lane & 15);
        int k0 = (lane >> 4) << 3;
        const float* src = &bio_w[n * 32 + k0];
        f4 a = *(const f4*)src, c = *(const f4*)(src + 4);
        unsigned* dst = (unsigned*)&bwFL[idx * 8];
        dst[0] = pack2(a[0], a[1]); dst[1] = pack2(a[2], a[3]);
        dst[2] = pack2(c[0], c[1]); dst[3] = pack2(c[2], c[3]);
    } else {                            // A = out_w @ Wv, cvec = out_w @ bv + out_b
        __shared__ float srow[256];
        __shared__ float red[256];
        int i = b - 100, j = t;
        srow[j] = out_w[i * 256 + j];
        __syncthreads();
        float acc = 0.f;
#pragma unroll 16
        for (int k = 0; k < 256; k++)
            acc = fmaf(srow[k], in_proj_w[(512 + k) * 256 + j], acc);
        A[i * 256 + j] = acc;
        red[j] = srow[j] * in_proj_b[512 + j];
        __syncthreads();
        for (int s = 128; s > 0; s >>= 1) {
            if (j < s) red[j] += red[j + s];
            __syncthreads();
        }
        if (j == 0) cvec[i] = red[0] + out_b[i];
    }
}

// =================== prep2: PQ weights (frag-linear bf16, LN-gain folded) + dvec ===================
__global__ __launch_bounds__(256) void k_prep_PQ(const float* __restrict__ cls1_w,
                                                 const float* __restrict__ cls1_b,
                                                 const float* __restrict__ A,
                                                 const float* __restrict__ cvec,
                                                 const float* __restrict__ ln_text_g,
                                                 const float* __restrict__ ln_text_b,
                                                 const float* __restrict__ ln_bio_g,
                                                 const float* __restrict__ ln_bio_b,
                                                 unsigned short* __restrict__ pqFL,
                                                 float* __restrict__ dvec) {
    __shared__ float w1[256], w2[256], red[256];
    int i = blockIdx.x, j = threadIdx.x;
    w1[j] = cls1_w[i * 512 + j];
    w2[j] = cls1_w[i * 512 + 256 + j];
    __syncthreads();
    float rp = 0.f, rq = 0.f;
#pragma unroll 8
    for (int k = 0; k < 256; k++) {
        float a = A[k * 256 + j];
        rp = fmaf(w1[k], a, rp);
        rq = fmaf(w2[k], a, rq);
    }
    int ct   = i >> 4;
    int lane = (i & 15) | (((j >> 3) & 3) << 4);
    int jj   = j & 7;
    int ks1  = j >> 5;
    pqFL[(((ks1     ) * 16 + ct) * 64 + lane) * 8 + jj] = f2bf(rp * ln_text_g[j]);
    pqFL[(((ks1 + 8 ) * 16 + ct) * 64 + lane) * 8 + jj] = f2bf(rq * ln_bio_g[j]);
    red[j] = rp * ln_text_b[j] + rq * ln_bio_b[j] + (w1[j] + w2[j]) * cvec[j];
    __syncthreads();
    for (int s = 128; s > 0; s >>= 1) {
        if (j < s) red[j] += red[j + s];
        __syncthreads();
    }
    if (j == 0) dvec[i] = red[0] + cls1_b[i];
}

// =================== kernel N: bio/text GEMMs + LN -> nbuf bf16 [rows][512] ===================
// 64 rows/block, 512 threads = 8 waves (cs = wv&3 col-slice of 64, rh = wv>>2 row-half).
// Text staged to LDS bf16 (sync, single buffer, round-2-proven). Small LDS -> 3 blocks/CU.
__global__ __launch_bounds__(512, 4) void k_N(
    const float* __restrict__ bio, const float* __restrict__ text,
    const float* __restrict__ bio_b, const float* __restrict__ text_b,
    const unsigned short* __restrict__ twFL, const unsigned short* __restrict__ bwFL,
    unsigned short* __restrict__ nbuf, int row0)
{
    __shared__ __align__(16) unsigned short s_x[64][200];  // 25.6 KB text chunk (K=192), +8 pad
    __shared__ float s_red[4][64][2];                      // 2 KB per-colslice row partials

    const int tid  = threadIdx.x;
    const int wv   = tid >> 6;
    const int cs   = wv & 3;
    const int rh   = wv >> 2;
    const int lane = tid & 63;
    const int q    = lane >> 4;
    const int lr   = lane & 15;
    const int R0   = blockIdx.x * 64;     // local row base (into nbuf)
    const int GR0  = row0 + R0;           // global row base (into bio/text)

    f4 acc[2][4];
    float s1[2][4], s2[2][4], m_[2][4], iv_[2][4];

    // ---------------- stage A: x_b = bio @ bio_w.T + bio_b ; n_b -> nbuf[.,256:512] ----------------
    {
        f4 bioA[2], bioB[2];
#pragma unroll
        for (int rt = 0; rt < 2; rt++) {
            const float* p = &bio[(size_t)(GR0 + rh * 32 + rt * 16 + lr) * 32 + q * 8];
            bioA[rt] = *(const f4*)p;
            bioB[rt] = *(const f4*)(p + 4);
        }
        s8 bfrb[4];
#pragma unroll
        for (int c = 0; c < 4; c++)
            bfrb[c] = *(const s8*)&bwFL[((cs * 4 + c) * 64 + lane) * 8];
#pragma unroll
        for (int rt = 0; rt < 2; rt++)
#pragma unroll
            for (int c = 0; c < 4; c++) acc[rt][c] = (f4){0.f, 0.f, 0.f, 0.f};
#pragma unroll
        for (int rt = 0; rt < 2; rt++) {
            s8 af = pack8(bioA[rt], bioB[rt]);
#pragma unroll
            for (int c = 0; c < 4; c++)
                acc[rt][c] = __builtin_amdgcn_mfma_f32_16x16x32_bf16(af, bfrb[c], acc[rt][c], 0, 0, 0);
        }
    }
#pragma unroll
    for (int rt = 0; rt < 2; rt++)
#pragma unroll
        for (int r = 0; r < 4; r++) { s1[rt][r] = 0.f; s2[rt][r] = 0.f; }
#pragma unroll
    for (int rt = 0; rt < 2; rt++)
#pragma unroll
        for (int c = 0; c < 4; c++) {
            float bb = bio_b[cs * 64 + c * 16 + lr];
#pragma unroll
            for (int r = 0; r < 4; r++) {
                float x = acc[rt][c][r] + bb;
                acc[rt][c][r] = x;
                s1[rt][r] += x; s2[rt][r] += x * x;
            }
        }
#pragma unroll
    for (int off = 1; off < 16; off <<= 1)
#pragma unroll
        for (int rt = 0; rt < 2; rt++)
#pragma unroll
            for (int r = 0; r < 4; r++) {
                s1[rt][r] += __shfl_xor(s1[rt][r], off, 64);
                s2[rt][r] += __shfl_xor(s2[rt][r], off, 64);
            }
    if (lr == 0)
#pragma unroll
        for (int rt = 0; rt < 2; rt++)
#pragma unroll
            for (int r = 0; r < 4; r++) {
                int row = rh * 32 + rt * 16 + q * 4 + r;
                s_red[cs][row][0] = s1[rt][r];
                s_red[cs][row][1] = s2[rt][r];
            }
    __syncthreads();
#pragma unroll
    for (int rt = 0; rt < 2; rt++)
#pragma unroll
        for (int r = 0; r < 4; r++) {
            int row = rh * 32 + rt * 16 + q * 4 + r;
            float t1 = s_red[0][row][0] + s_red[1][row][0] + s_red[2][row][0] + s_red[3][row][0];
            float t2 = s_red[0][row][1] + s_red[1][row][1] + s_red[2][row][1] + s_red[3][row][1];
            float mm = t1 * (1.f / 256.f);
            float vv = t2 * (1.f / 256.f) - mm * mm;
            m_[rt][r]  = mm;
            iv_[rt][r] = rsqrtf(vv + EPS);
        }
#pragma unroll
    for (int rt = 0; rt < 2; rt++)
#pragma unroll
        for (int c = 0; c < 4; c++) {
            int col = 256 + cs * 64 + c * 16 + lr;
#pragma unroll
            for (int r = 0; r < 4; r++)
                nbuf[(size_t)(R0 + rh * 32 + rt * 16 + q * 4 + r) * 512 + col] =
                    f2bf((acc[rt][c][r] - m_[rt][r]) * iv_[rt][r]);
        }

    // ---------------- stage B: x_t = text @ text_w.T + text_b (K=768, 4 chunks) ----------------
#pragma unroll
    for (int rt = 0; rt < 2; rt++)
#pragma unroll
        for (int c = 0; c < 4; c++) acc[rt][c] = (f4){0.f, 0.f, 0.f, 0.f};

    for (int ch = 0; ch < 4; ch++) {
        __syncthreads();                  // prev chunk reads done (and stage-A s_red reads, first iter)
#pragma unroll
        for (int i = 0; i < 6; i++) {
            int idx = tid + i * 512;      // 3072 f4-slots: 64 rows x 48
            int row = idx / 48;
            int c4  = idx - row * 48;
            f4 v = *(const f4*)&text[(size_t)(GR0 + row) * 768 + ch * 192 + c4 * 4];
            uint2 p; p.x = pack2(v[0], v[1]); p.y = pack2(v[2], v[3]);
            *(uint2*)&s_x[row][c4 * 4] = p;
        }
        __syncthreads();                  // chunk staged
        int ksg0 = ch * 6;
#pragma unroll
        for (int ks = 0; ks < 6; ks++) {
            s8 bfr[4];
#pragma unroll
            for (int c = 0; c < 4; c++)
                bfr[c] = *(const s8*)&twFL[(((ksg0 + ks) * 16 + cs * 4 + c) * 64 + lane) * 8];
#pragma unroll
            for (int rt = 0; rt < 2; rt++) {
                s8 af = *(const s8*)&s_x[rh * 32 + rt * 16 + lr][ks * 32 + q * 8];
#pragma unroll
                for (int c = 0; c < 4; c++)
                    acc[rt][c] = __builtin_amdgcn_mfma_f32_16x16x32_bf16(af, bfr[c], acc[rt][c], 0, 0, 0);
            }
        }
    }
    // bias + LN stats + n_t -> nbuf[.,0:256]
#pragma unroll
    for (int rt = 0; rt < 2; rt++)
#pragma unroll
        for (int r = 0; r < 4; r++) { s1[rt][r] = 0.f; s2[rt][r] = 0.f; }
#pragma unroll
    for (int rt = 0; rt < 2; rt++)
#pragma unroll
        for (int c = 0; c < 4; c++) {
            float bb = text_b[cs * 64 + c * 16 + lr];
#pragma unroll
            for (int r = 0; r < 4; r++) {
                float x = acc[rt][c][r] + bb;
                acc[rt][c][r] = x;
                s1[rt][r] += x; s2[rt][r] += x * x;
            }
        }
#pragma unroll
    for (int off = 1; off < 16; off <<= 1)
#pragma unroll
        for (int rt = 0; rt < 2; rt++)
#pragma unroll
            for (int r = 0; r < 4; r++) {
                s1[rt][r] += __shfl_xor(s1[rt][r], off, 64);
                s2[rt][r] += __shfl_xor(s2[rt][r], off, 64);
            }
    if (lr == 0)                          // stage-A s_red reads finished before chunk-0 barrier
#pragma unroll
        for (int rt = 0; rt < 2; rt++)
#pragma unroll
            for (int r = 0; r < 4; r++) {
                int row = rh * 32 + rt * 16 + q * 4 + r;
                s_red[cs][row][0] = s1[rt][r];
                s_red[cs][row][1] = s2[rt][r];
            }
    __syncthreads();
#pragma unroll
    for (int rt = 0; rt < 2; rt++)
#pragma unroll
        for (int r = 0; r < 4; r++) {
            int row = rh * 32 + rt * 16 + q * 4 + r;
            float t1 = s_red[0][row][0] + s_red[1][row][0] + s_red[2][row][0] + s_red[3][row][0];
            float t2 = s_red[0][row][1] + s_red[1][row][1] + s_red[2][row][1] + s_red[3][row][1];
            float mm = t1 * (1.f / 256.f);
            float vv = t2 * (1.f / 256.f) - mm * mm;
            m_[rt][r]  = mm;
            iv_[rt][r] = rsqrtf(vv + EPS);
        }
#pragma unroll
    for (int rt = 0; rt < 2; rt++)
#pragma unroll
        for (int c = 0; c < 4; c++) {
            int col = cs * 64 + c * 16 + lr;
#pragma unroll
            for (int r = 0; r < 4; r++)
                nbuf[(size_t)(R0 + rh * 32 + rt * 16 + q * 4 + r) * 512 + col] =
                    f2bf((acc[rt][c][r] - m_[rt][r]) * iv_[rt][r]);
        }
}

// =================== kernel Z: z = Wpq @ n + dvec ; LN ; relu ; cls2 -> out ===================
// 64 rows/block, 512 threads = 8 waves. Single tight K-loop (16 ksteps), no barriers in loop,
// no staging LDS. n A-frags from global (L2-hot, written by k_N); pq B-frags from L2.
__global__ __launch_bounds__(512, 4) void k_Z(
    const unsigned short* __restrict__ nbuf,
    const unsigned short* __restrict__ pqFL,
    const float* __restrict__ dvec,
    const float* __restrict__ cls_ln_g, const float* __restrict__ cls_ln_b,
    const float* __restrict__ cls2_w, const float* __restrict__ cls2_b,
    float* __restrict__ out, int row0)
{
    __shared__ float s_red[4][64][2];

    const int tid  = threadIdx.x;
    const int wv   = tid >> 6;
    const int cs   = wv & 3;
    const int rh   = wv >> 2;
    const int lane = tid & 63;
    const int q    = lane >> 4;
    const int lr   = lane & 15;
    const int R0   = blockIdx.x * 64;     // local rows (nbuf)
    const int GR0  = row0 + R0;           // global rows (out)

    f4 acc[2][4];
    float s1[2][4], s2[2][4], m_[2][4], iv_[2][4];

#pragma unroll
    for (int rt = 0; rt < 2; rt++)
#pragma unroll
        for (int c = 0; c < 4; c++) {
            float dv = dvec[cs * 64 + c * 16 + lr];
            acc[rt][c] = (f4){dv, dv, dv, dv};
        }
    const unsigned short* nb0 = &nbuf[(size_t)(R0 + rh * 32 + lr) * 512 + q * 8];
#pragma unroll 4
    for (int ks = 0; ks < 16; ks++) {
        s8 bfr[4];
#pragma unroll
        for (int c = 0; c < 4; c++)
            bfr[c] = *(const s8*)&pqFL[((ks * 16 + cs * 4 + c) * 64 + lane) * 8];
        s8 af0 = *(const s8*)&nb0[ks * 32];
        s8 af1 = *(const s8*)&nb0[16 * 512 + ks * 32];
#pragma unroll
        for (int c = 0; c < 4; c++) {
            acc[0][c] = __builtin_amdgcn_mfma_f32_16x16x32_bf16(af0, bfr[c], acc[0][c], 0, 0, 0);
            acc[1][c] = __builtin_amdgcn_mfma_f32_16x16x32_bf16(af1, bfr[c], acc[1][c], 0, 0, 0);
        }
    }

    // ---------------- epilogue: LN(z), relu, cls2 ----------------
#pragma unroll
    for (int rt = 0; rt < 2; rt++)
#pragma unroll
        for (int r = 0; r < 4; r++) { s1[rt][r] = 0.f; s2[rt][r] = 0.f; }
#pragma unroll
    for (int rt = 0; rt < 2; rt++)
#pragma unroll
        for (int c = 0; c < 4; c++)
#pragma unroll
            for (int r = 0; r < 4; r++) {
                float x = acc[rt][c][r];
                s1[rt][r] += x; s2[rt][r] += x * x;
            }
#pragma unroll
    for (int off = 1; off < 16; off <<= 1)
#pragma unroll
        for (int rt = 0; rt < 2; rt++)
#pragma unroll
            for (int r = 0; r < 4; r++) {
                s1[rt][r] += __shfl_xor(s1[rt][r], off, 64);
                s2[rt][r] += __shfl_xor(s2[rt][r], off, 64);
            }
    if (lr == 0)
#pragma unroll
        for (int rt = 0; rt < 2; rt++)
#pragma unroll
            for (int r = 0; r < 4; r++) {
                int row = rh * 32 + rt * 16 + q * 4 + r;
                s_red[cs][row][0] = s1[rt][r];
                s_red[cs][row][1] = s2[rt][r];
            }
    __syncthreads();
#pragma unroll
    for (int rt = 0; rt < 2; rt++)
#pragma unroll
        for (int r = 0; r < 4; r++) {
            int row = rh * 32 + rt * 16 + q * 4 + r;
            float t1 = s_red[0][row][0] + s_red[1][row][0] + s_red[2][row][0] + s_red[3][row][0];
            float t2 = s_red[0][row][1] + s_red[1][row][1] + s_red[2][row][1] + s_red[3][row][1];
            float mm = t1 * (1.f / 256.f);
            float vv = t2 * (1.f / 256.f) - mm * mm;
            m_[rt][r]  = mm;
            iv_[rt][r] = rsqrtf(vv + EPS);
        }
    float po0[2][4], po1[2][4];
#pragma unroll
    for (int rt = 0; rt < 2; rt++)
#pragma unroll
        for (int r = 0; r < 4; r++) { po0[rt][r] = 0.f; po1[rt][r] = 0.f; }
#pragma unroll
    for (int rt = 0; rt < 2; rt++)
#pragma unroll
        for (int c = 0; c < 4; c++) {
            int col = cs * 64 + c * 16 + lr;
            float gg = cls_ln_g[col], bb = cls_ln_b[col];
            float c0 = cls2_w[col],   c1 = cls2_w[256 + col];
#pragma unroll
            for (int r = 0; r < 4; r++) {
                float h = fmaxf((acc[rt][c][r] - m_[rt][r]) * iv_[rt][r] * gg + bb, 0.f);
                po0[rt][r] = fmaf(h, c0, po0[rt][r]);
                po1[rt][r] = fmaf(h, c1, po1[rt][r]);
            }
        }
#pragma unroll
    for (int off = 1; off < 16; off <<= 1)
#pragma unroll
        for (int rt = 0; rt < 2; rt++)
#pragma unroll
            for (int r = 0; r < 4; r++) {
                po0[rt][r] += __shfl_xor(po0[rt][r], off, 64);
                po1[rt][r] += __shfl_xor(po1[rt][r], off, 64);
            }
    __syncthreads();                      // stats reads done; reuse s_red
    if (lr == 0)
#pragma unroll
        for (int rt = 0; rt < 2; rt++)
#pragma unroll
            for (int r = 0; r < 4; r++) {
                int row = rh * 32 + rt * 16 + q * 4 + r;
                s_red[cs][row][0] = po0[rt][r];
                s_red[cs][row][1] = po1[rt][r];
            }
    __syncthreads();
    if (tid < 128) {
        int row = tid >> 1, comp = tid & 1;
        float v = s_red[0][row][comp] + s_red[1][row][comp] +
                  s_red[2][row][comp] + s_red[3][row][comp];
        out[(size_t)(GR0 + row) * 2 + comp] = v + cls2_b[comp];
    }
}

// ======================= launch =======================
extern "C" void kernel_launch(void* const* d_in, const int* in_sizes, int n_in,
                              void* d_out, int out_size, void* d_ws, size_t ws_size,
                              hipStream_t stream) {
    const float* bio       = (const float*)d_in[0];
    const float* text      = (const float*)d_in[1];
    const float* bio_w     = (const float*)d_in[2];
    const float* bio_b     = (const float*)d_in[3];
    const float* text_w    = (const float*)d_in[4];
    const float* text_b    = (const float*)d_in[5];
    const float* ln_bio_g  = (const float*)d_in[6];
    const float* ln_bio_b  = (const float*)d_in[7];
    const float* ln_text_g = (const float*)d_in[8];
    const float* ln_text_b = (const float*)d_in[9];
    const float* in_proj_w = (const float*)d_in[10];
    const float* in_proj_b = (const float*)d_in[11];
    const float* out_w     = (const float*)d_in[12];
    const float* out_b     = (const float*)d_in[13];
    const float* cls1_w    = (const float*)d_in[14];
    const float* cls1_b    = (const float*)d_in[15];
    const float* cls_ln_g  = (const float*)d_in[16];
    const float* cls_ln_b  = (const float*)d_in[17];
    const float* cls2_w    = (const float*)d_in[18];
    const float* cls2_b    = (const float*)d_in[19];
    float* out = (float*)d_out;

    float* ws   = (float*)d_ws;
    float* A    = ws;                 // 65536 fp32
    float* cvec = ws + 65536;         // 256
    float* dvec = ws + 65792;         // 256
    unsigned short* us   = (unsigned short*)(ws + 66048);
    unsigned short* twFL = us;            // 196608 bf16
    unsigned short* bwFL = us + 196608;   // 8192
    unsigned short* pqFL = us + 204800;   // 131072
    unsigned short* nbuf = us + 335872;   // [chunk_rows][512] bf16
    size_t used_bytes = (size_t)66048 * 4 + (size_t)335872 * 2;   // 935936

    int nrows = in_sizes[0] / 32;     // 65536

    // rows of n that fit in remaining workspace (1024 B/row), multiple of 64
    size_t avail = ws_size > used_bytes ? ws_size - used_bytes : 0;
    long maxrows = (long)(avail / 1024);
    int chunk = (int)((maxrows / 64) * 64);
    if (chunk > nrows) chunk = nrows;
    if (chunk < 64) chunk = 64;       // ws is known >=1.6MB from prior rounds; this never binds

    k_prep1  <<<356, 256, 0, stream>>>(text_w, bio_w, out_w, in_proj_w, in_proj_b, out_b,
                                       twFL, bwFL, A, cvec);
    k_prep_PQ<<<256, 256, 0, stream>>>(cls1_w, cls1_b, A, cvec,
                                       ln_text_g, ln_text_b, ln_bio_g, ln_bio_b,
                                       pqFL, dvec);

    for (int r0 = 0; r0 < nrows; r0 += chunk) {
        int rows = nrows - r0 < chunk ? nrows - r0 : chunk;
        k_N<<<rows / 64, 512, 0, stream>>>(bio, text, bio_b, text_b,
                                           twFL, bwFL, nbuf, r0);
        k_Z<<<rows / 64, 512, 0, stream>>>(nbuf, pqFL, dvec,
                                           cls_ln_g, cls_ln_b, cls2_w, cls2_b,
                                           out, r0);
    }
}